// Round 1
// baseline (581.154 us; speedup 1.0000x reference)
//
#include <hip/hip_runtime.h>
#include <stdint.h>

// Persistent-kernel LSTM NAS controller rollout — FLAG-GATED BULK-READ comms.
// r10 experiment: replace per-cell tag-polling (32K threads x sc1 loads
// perpetually outstanding -> XCD<->MALL queue congestion, ~4.4us/hop) with:
//   producer: plain 4B float stores (sc1) -> s_waitcnt vmcnt(0) (per-wave
//   drain = architectural agent-release) -> barrier -> ONE flag store per WG.
//   consumer: ONE wave per WG polls the 64-flag array (4 lines), acquire
//   fence, barrier, then ALL waves bulk-read data ONCE (relaxed sc1 loads).
// Poll traffic: ~4096 -> ~256 line-req/period device-wide; payload halves.
// Flag progression is phase-gated (no WG can advance a flag array by 2 tags
// while any WG still polls the older tag), so single data buffers are
// race-free; monotonic tags make graph-replay safe (stale finals 64/65
// never match an early poll target).
// Arithmetic identical to r9 kernel (bit-exact): threefry2x32, gumbel,
// wredsum butterfly, tanhf/sigm orders unchanged.
// Hops/step = 2 (structural minimum; partial-sum redistributions raise it).

#define KWG    64
#define NTH    512
#define LSTEPS 32
#define DDIM   512
#define NOPS   16
#define NEGC   (-1.0e9f)

// ---------------- threefry2x32 core ----------------
static __device__ __forceinline__ void tf2x32(uint32_t k0, uint32_t k1,
                                              uint32_t c0, uint32_t c1,
                                              uint32_t& o0, uint32_t& o1){
  uint32_t ks2 = k0 ^ k1 ^ 0x1BD11BDAu;
  uint32_t x0 = c0 + k0;
  uint32_t x1 = c1 + k1;
#define TFR(r) { x0 += x1; x1 = (x1 << (r)) | (x1 >> (32 - (r))); x1 ^= x0; }
  TFR(13) TFR(15) TFR(26) TFR(6)
  x0 += k1;  x1 += ks2 + 1u;
  TFR(17) TFR(29) TFR(16) TFR(24)
  x0 += ks2; x1 += k0 + 2u;
  TFR(13) TFR(15) TFR(26) TFR(6)
  x0 += k0;  x1 += k1 + 3u;
  TFR(17) TFR(29) TFR(16) TFR(24)
  x0 += k1;  x1 += ks2 + 4u;
  TFR(13) TFR(15) TFR(26) TFR(6)
  x0 += ks2; x1 += k0 + 5u;
#undef TFR
  o0 = x0; o1 = x1;
}

static __device__ __forceinline__ float gumbel_bits(uint32_t bits){
  float f = __uint_as_float((bits >> 9) | 0x3f800000u) - 1.0f;
  float u = (f == 0.0f) ? 1.1754943508222875e-38f : f;
  return -logf(-logf(u));
}

static __device__ __forceinline__ float sigm(float x){
  return 1.0f / (1.0f + expf(-x));
}

static __device__ __forceinline__ float wredsum(float v){
  #pragma unroll
  for (int m = 32; m; m >>= 1) v += __shfl_xor(v, m, 64);
  return v;
}

// gather 8 elems at stride 64: d = 64k + lane  (plain; LDS/global constants)
static __device__ __forceinline__ void gl8(const float* __restrict__ p, int lane, float* r){
  #pragma unroll
  for (int k = 0; k < 8; ++k) r[k] = p[(k << 6) + lane];
}

static __device__ __forceinline__ float dot8(const float* w, const float* x){
  float s = 0.f;
  #pragma unroll
  for (int k = 0; k < 8; ++k) s += w[k]*x[k];
  return s;
}

// ---------------- agent-scope comm helpers ----------------
static __device__ __forceinline__ float agld(float* p){
  return __hip_atomic_load(p, __ATOMIC_RELAXED, __HIP_MEMORY_SCOPE_AGENT);
}
static __device__ __forceinline__ void agst(float* p, float v){
  __hip_atomic_store(p, v, __ATOMIC_RELAXED, __HIP_MEMORY_SCOPE_AGENT);
}
// one-shot bulk read, stride-64 (d = 64k + lane), bypassing stale caches
static __device__ __forceinline__ void gld8(float* p, int lane, float* r){
  #pragma unroll
  for (int k = 0; k < 8; ++k) r[k] = agld(p + (k << 6) + lane);
}
// wave polls 64 per-WG flags (lane -> flag[lane]); exits when all == tag
static __device__ __forceinline__ void pollflag(uint32_t* f, int lane, uint32_t tag){
  for (;;){
    uint32_t v = __hip_atomic_load(f + lane, __ATOMIC_RELAXED, __HIP_MEMORY_SCOPE_AGENT);
    if (__all(v == tag)) break;
    __builtin_amdgcn_s_sleep(1);
  }
  __builtin_amdgcn_fence(__ATOMIC_ACQUIRE, "agent");
}

__global__ void __launch_bounds__(NTH, 2)
Controller_60601988547087_kernel(const float* __restrict__ emb,
                                 const float* __restrict__ wih,
                                 const float* __restrict__ whh,
                                 const float* __restrict__ bih,
                                 const float* __restrict__ bhh,
                                 const float* __restrict__ wa1,
                                 const float* __restrict__ wa2,
                                 const float* __restrict__ idxfc,
                                 const float* __restrict__ opfc,
                                 float* __restrict__ out,
                                 uint64_t* __restrict__ ws64)
{
  const int tid  = threadIdx.x;
  const int wg   = blockIdx.x;
  const int wave = tid >> 6;              // 0..7
  const int lane = tid & 63;
  const int unit = (wg << 3) | wave;      // one hidden unit per wave, 512 total

  // workspace: flags (own lines) then plain-float data buffers
  uint32_t* flagA = (uint32_t*)ws64;          // [64], bytes 0..255
  uint32_t* flagB = flagA + 64;               // [64], bytes 256..511
  float* h0f   = (float*)(ws64 + 64);         // [512] init h0
  float* h1f   = h0f  + DDIM;                 // [512] hop-A payload
  float* hw2f  = h1f  + DDIM;                 // [512] hop-B payload
  float* aw1f  = hw2f + DDIM;                 // [32][512] anchor W1 rows
  float* candf = aw1f + 32*DDIM;              // [33][512] h2 candidates

  __shared__ float s_xproj[17 * 32];          // [op][wave][gate] W_ih·emb[op]
  __shared__ float s_aproj[33 * 33];          // [row][wave*4+g] stride 33
  __shared__ float s_opfc[NOPS * DDIM];       // 32 KB op_fc
  __shared__ float s_logits[33];
  __shared__ float s_oplog[16];
  __shared__ int   s_ibc[2];

  // ---- weights register-stationary, gathered at d = 64k+lane ----
  float wihr[4][8], whhr[4][8], a1r[8], a2r[8], fcr[8], bsum[4];
  #pragma unroll
  for (int g = 0; g < 4; ++g){
    gl8(wih + (size_t)((g << 9) + unit) * DDIM, lane, wihr[g]);
    gl8(whh + (size_t)((g << 9) + unit) * DDIM, lane, whhr[g]);
    bsum[g] = bih[(g << 9) + unit] + bhh[(g << 9) + unit];
  }
  gl8(wa1 + (size_t)unit * DDIM, lane, a1r);
  gl8(wa2 + (size_t)unit * DDIM, lane, a2r);
  gl8(idxfc, lane, fcr);

  for (int i = tid; i < NOPS * DDIM; i += NTH) s_opfc[i] = opfc[i];
  if (tid < 33) s_aproj[tid] = 0.0f;      // aproj row 0: anchors[0] = zeros

  // ---- static x-projections ----
  for (int op = 0; op <= NOPS; ++op){
    float xc[8];
    gl8(emb + (size_t)op * DDIM, lane, xc);
    #pragma unroll
    for (int g = 0; g < 4; ++g){
      float xp = wredsum(dot8(wihr[g], xc));
      if (lane == 0) s_xproj[op * 32 + (wave << 2) + g] = xp;
    }
  }
  __syncthreads();

  // per-wave register cache of aw1 rows (row r owned by wave r&7, slot r>>3)
  float row0[8], row1[8], row2[8], row3[8];

  // ---- init: h0 = cell(emb[16],0,0); publish to h0f, flagA tag 1 ----
  float cst;
  {
    const float* xp = s_xproj + 16 * 32 + (wave << 2);
    float gi = sigm(xp[0] + bsum[0]);
    float go = sigm(xp[3] + bsum[3]);
    cst = gi * tanhf(xp[2] + bsum[2]);   // c=0: forget term vanishes exactly
    float h0 = go * tanhf(cst);
    if (lane == 0) agst(h0f + unit, h0);
  }
  asm volatile("s_waitcnt vmcnt(0)" ::: "memory");
  __syncthreads();
  if (tid == 0)
    __hip_atomic_store(flagA + wg, 1u, __ATOMIC_RELAXED, __HIP_MEMORY_SCOPE_AGENT);
  if (wave == 0) pollflag(flagA, lane, 1u);
  __syncthreads();

  float hc8[8];
  gld8(h0f, lane, hc8);                  // carry h (= h0), register-resident

  uint32_t key0 = 0u, key1v = 42u;       // jax.random.key(42) -> (0, 42)
  float ent_sum = 0.f, lp_sum = 0.f;
  int prev_op = NOPS;                    // inp0 = embedding[16]

  for (int t = 0; t < LSTEPS; ++t){
    const uint32_t tagA = 2u*(uint32_t)t + 2u;
    const uint32_t tagB = 2u*(uint32_t)t + 3u;

    // ========== Stage A: cell1; publish h1, aw1 row t; aproj row t ==========
    {
      const float* xp = s_xproj + prev_op * 32 + (wave << 2);
      float p0 = wredsum(dot8(whhr[0], hc8));
      float p1 = wredsum(dot8(whhr[1], hc8));
      float p2 = wredsum(dot8(whhr[2], hc8));
      float p3 = wredsum(dot8(whhr[3], hc8));
      float gi = sigm(xp[0] + p0 + bsum[0]);
      float gf = sigm(xp[1] + p1 + bsum[1]);
      float go = sigm(xp[3] + p3 + bsum[3]);
      cst = gf * cst + gi * tanhf(xp[2] + p2 + bsum[2]);
      float hn = go * tanhf(cst);
      if (lane == 0) agst(h1f + unit, hn);
      float pa = wredsum(dot8(a1r, hc8));              // aw1 row t = W1·h2^(t-1)
      if (lane == 0) agst(aw1f + (size_t)t * DDIM + unit, pa);
      if (t > 0){                                      // aproj[t] = W_ih·anchors[t]
        #pragma unroll
        for (int g = 0; g < 4; ++g){
          float ap = wredsum(dot8(wihr[g], hc8));
          if (lane == 0) s_aproj[t * 33 + (wave << 2) + g] = ap;
        }
      }
    }
    asm volatile("s_waitcnt vmcnt(0)" ::: "memory");   // per-wave agent-release drain
    __syncthreads();
    if (tid == 0)
      __hip_atomic_store(flagA + wg, tagA, __ATOMIC_RELAXED, __HIP_MEMORY_SCOPE_AGENT);
    if (wave == 0) pollflag(flagA, lane, tagA);        // hop A
    __syncthreads();

    // owner caches aw1 row t (one-shot bulk read; data guaranteed visible)
    if (wave == (t & 7)){
      float* rb = aw1f + (size_t)t * DDIM;
      int slot = t >> 3;
      if      (slot == 0) gld8(rb, lane, row0);
      else if (slot == 1) gld8(rb, lane, row1);
      else if (slot == 2) gld8(rb, lane, row2);
      else                gld8(rb, lane, row3);
    }
    float h18[8];
    gld8(h1f, lane, h18);

    // ========== Stage B: publish hw2; ghh + h2 candidates; flagB ==========
    {
      float q = wredsum(dot8(a2r, h18));
      if (lane == 0) agst(hw2f + unit, q);
    }
    float ghh0 = wredsum(dot8(whhr[0], h18));
    float ghh1 = wredsum(dot8(whhr[1], h18));
    float ghh2 = wredsum(dot8(whhr[2], h18));
    float ghh3 = wredsum(dot8(whhr[3], h18));
    float cst_cand = 0.f;
    if (lane <= t){                                    // lane i owns candidate i
      const float* ag = s_aproj + lane * 33 + (wave << 2);
      float gi = sigm(ag[0] + ghh0 + bsum[0]);
      float gf = sigm(ag[1] + ghh1 + bsum[1]);
      float go = sigm(ag[3] + ghh3 + bsum[3]);
      cst_cand = gf * cst + gi * tanhf(ag[2] + ghh2 + bsum[2]);
      float h2c = go * tanhf(cst_cand);
      agst(candf + (size_t)lane * DDIM + unit, h2c);
    }
    asm volatile("s_waitcnt vmcnt(0)" ::: "memory");
    __syncthreads();
    if (tid == 0)
      __hip_atomic_store(flagB + wg, tagB, __ATOMIC_RELAXED, __HIP_MEMORY_SCOPE_AGENT);
    if (wave == 0) pollflag(flagB, lane, tagB);        // hop B
    __syncthreads();

    // ======== Node logits + sampling — EVERY WG, bit-identical ========
    int ni;
    float nlp_s = 0.f, nent_s = 0.f;
    uint32_t k2a_s = 0u, k2b_s = 0u;
    {
      float hw28[8];
      gld8(hw2f, lane, hw28);
#define ROWDOT(RR, I)                                                          \
      { int i_ = (I);                                                          \
        if (i_ <= t){                                                          \
          float acc = 0.f;                                                     \
          _Pragma("unroll")                                                    \
          for (int k = 0; k < 8; ++k) acc += tanhf(RR[k] + hw28[k]) * fcr[k];  \
          acc = wredsum(acc);                                                  \
          if (lane == 0) s_logits[i_] = 2.5f * tanhf(acc / 5.0f);              \
        } }
      ROWDOT(row0, wave)
      ROWDOT(row1, wave + 8)
      ROWDOT(row2, wave + 16)
      ROWDOT(row3, wave + 24)
#undef ROWDOT
      __syncthreads();
      if (wave == 0){
        // split(key,3), partitionable/foldlike: row i = tf(key, (0, i))
        uint32_t s0 = 0, s1 = 0;
        if (lane < 3) tf2x32(key0, key1v, 0u, (uint32_t)lane, s0, s1);
        uint32_t k1a = __shfl(s0, 0, 64), k1b = __shfl(s1, 0, 64);
        k2a_s = __shfl(s0, 1, 64); k2b_s = __shfl(s1, 1, 64);
        uint32_t nk0 = __shfl(s0, 2, 64), nk1 = __shfl(s1, 2, 64);
        key0 = nk0; key1v = nk1;
        // 33 random bits: bits[i] = x0 ^ x1 of tf(k1, (0, i))
        uint32_t y0 = 0, y1 = 0;
        if (lane < 33) tf2x32(k1a, k1b, 0u, (uint32_t)lane, y0, y1);
        uint32_t bits = y0 ^ y1;
        float gmb   = gumbel_bits(bits);
        float logit = (lane < 33) ? ((lane <= t) ? s_logits[lane] : NEGC) : -3.0e38f;
        float cand  = (lane < 33) ? (logit + gmb) : -3.0e38f;
        float v = cand; int bi = lane;
        #pragma unroll
        for (int m = 32; m; m >>= 1){
          float ov = __shfl_xor(v, m, 64); int ob = __shfl_xor(bi, m, 64);
          if (ov > v || (ov == v && ob < bi)){ v = ov; bi = ob; }
        }
        int ni_ = bi;
        float lm = (lane < 33) ? logit : -3.0e38f;
        #pragma unroll
        for (int m = 32; m; m >>= 1) lm = fmaxf(lm, __shfl_xor(lm, m, 64));
        float ex   = (lane < 33) ? expf(logit - lm) : 0.f;
        float ssum = wredsum(ex);
        float lsm  = logit - lm - logf(ssum);
        nlp_s  = -__shfl(lsm, ni_, 64);
        float entc = (lane <= t) ? (-lsm * expf(lsm)) : 0.f;
        nent_s = wredsum(entc);
        if (lane == 0) s_ibc[0] = ni_;
      }
      __syncthreads();
      ni = s_ibc[0];
    }

    // ========== Select h2 = cand[ni] (covered by flagB; one-shot read) ====
    cst = __shfl(cst_cand, ni, 64);                    // own unit's cst
    gld8(candf + (size_t)ni * DDIM, lane, hc8);        // next carry, to regs

    // ========== Tail (local): op logits + sample -> prev_op ==========
    {
      #pragma unroll
      for (int jj = 0; jj < 2; ++jj){
        int i = wave + (jj << 3);
        float acc = 0.f;
        #pragma unroll
        for (int k = 0; k < 8; ++k) acc += s_opfc[i * DDIM + (k << 6) + lane] * hc8[k];
        acc = wredsum(acc);
        if (lane == 0) s_oplog[i] = tanhf(acc / 5.0f);  // (2.5/2.5)=1 scale
      }
      __syncthreads();
    }
    int oi;
    {
      if (wave == 0){
        // 16 random bits: bits[i] = x0 ^ x1 of tf(k2, (0, i))
        uint32_t z0 = 0, z1 = 0;
        if (lane < 16) tf2x32(k2a_s, k2b_s, 0u, (uint32_t)lane, z0, z1);
        uint32_t bits = z0 ^ z1;
        float gmb   = gumbel_bits(bits);
        float logit = (lane < 16) ? s_oplog[lane] : -3.0e38f;
        float cand  = (lane < 16) ? (logit + gmb) : -3.0e38f;
        float v = cand; int bi = lane;
        #pragma unroll
        for (int m = 32; m; m >>= 1){
          float ov = __shfl_xor(v, m, 64); int ob = __shfl_xor(bi, m, 64);
          if (ov > v || (ov == v && ob < bi)){ v = ov; bi = ob; }
        }
        int oi_ = bi;
        float lm = (lane < 16) ? logit : -3.0e38f;
        #pragma unroll
        for (int m = 32; m; m >>= 1) lm = fmaxf(lm, __shfl_xor(lm, m, 64));
        float ex   = (lane < 16) ? expf(logit - lm) : 0.f;
        float ssum = wredsum(ex);
        float olsm = logit - lm - logf(ssum);
        float olp  = -__shfl(olsm, oi_, 64);
        float oent = wredsum((lane < 16) ? (-olsm * expf(olsm)) : 0.f);
        lp_sum  += nlp_s + olp;
        ent_sum += nent_s + oent;
        if (lane == 0){
          s_ibc[1] = oi_;
          if (wg == 0){
            out[2 * t]     = (float)ni;
            out[2 * t + 1] = (float)oi_;
          }
        }
      }
      __syncthreads();
      oi = s_ibc[1];
    }
    prev_op = oi;
  }

  if (wg == 0 && wave == 0 && lane == 0){
    out[64] = ent_sum;
    out[65] = lp_sum;
  }
}

extern "C" void kernel_launch(void* const* d_in, const int* in_sizes, int n_in,
                              void* d_out, int out_size, void* d_ws, size_t ws_size,
                              hipStream_t stream) {
  (void)in_sizes; (void)n_in; (void)out_size; (void)ws_size;
  const float* emb  = (const float*)d_in[0];
  const float* wih  = (const float*)d_in[1];
  const float* whh  = (const float*)d_in[2];
  const float* bih  = (const float*)d_in[3];
  const float* bhh  = (const float*)d_in[4];
  const float* wa1  = (const float*)d_in[5];
  const float* wa2  = (const float*)d_in[6];
  const float* ifc  = (const float*)d_in[7];
  const float* ofc  = (const float*)d_in[8];
  float* out = (float*)d_out;
  uint64_t* ws = (uint64_t*)d_ws;
  hipLaunchKernelGGL(Controller_60601988547087_kernel,
                     dim3(KWG), dim3(NTH), 0, stream,
                     emb, wih, whh, bih, bhh, wa1, wa2, ifc, ofc, out, ws);
}